// Round 1
// baseline (2280.922 us; speedup 1.0000x reference)
//
#include <hip/hip_runtime.h>

constexpr int D  = 256;
constexpr int K  = 8192;
constexpr int N  = 32768;   // B*S

constexpr int BM = 128;     // z rows per block
constexpr int BN = 128;     // codes per k-tile
constexpr int TD = 32;      // d-chunk for codebook staging
constexpr int ZS = 260;     // z LDS stride (floats): 260*4B % 16 == 0, banks spread
constexpr int CS = 36;      // cb LDS stride (floats)

// e_sq[k] = sum_d cb[k][d]^2 ; one wave per code, coalesced float4 loads
__global__ void esq_kernel(const float* __restrict__ cb, float* __restrict__ esq) {
    const int lane = threadIdx.x & 63;
    const int code = (int)((blockIdx.x * (size_t)blockDim.x + threadIdx.x) >> 6);
    const float4 v = *reinterpret_cast<const float4*>(cb + (size_t)code * D + lane * 4);
    float s = v.x * v.x + v.y * v.y + v.z * v.z + v.w * v.w;
    #pragma unroll
    for (int m = 32; m >= 1; m >>= 1) s += __shfl_xor(s, m);
    if (lane == 0) esq[code] = s;
}

// Fused dist-GEMM + argmin + gather.
// Block: 256 threads as 16x16 (tx = code dim, ty = row dim), 8x8 per thread.
__launch_bounds__(256)
__global__ void vq_kernel(const float* __restrict__ z, const float* __restrict__ cb,
                          const float* __restrict__ esq, float* __restrict__ out) {
    __shared__ float zs[BM * ZS];   // 133,120 B — full z tile, staged once
    __shared__ float cs[BN * CS];   //  18,432 B — codebook d-chunk

    const int tid = threadIdx.x;
    const int tx  = tid & 15;
    const int ty  = tid >> 4;
    const size_t row0 = (size_t)blockIdx.x * BM;

    // Stage z tile: 128 rows x 256 floats = 8192 float4, 32 per thread.
    // Each wave loads one full row per step -> 1KB contiguous, coalesced.
    #pragma unroll
    for (int i = 0; i < 32; ++i) {
        int f  = tid + i * 256;        // float4 index in tile
        int r  = f >> 6;
        int c4 = (f & 63) * 4;
        *reinterpret_cast<float4*>(&zs[r * ZS + c4]) =
            *reinterpret_cast<const float4*>(z + (row0 + r) * D + c4);
    }

    float minv[8];
    int   mini[8];
    #pragma unroll
    for (int i = 0; i < 8; ++i) { minv[i] = 3.4e38f; mini[i] = 0; }

    for (int k0 = 0; k0 < K; k0 += BN) {
        float acc[8][8];
        #pragma unroll
        for (int i = 0; i < 8; ++i)
            #pragma unroll
            for (int j = 0; j < 8; ++j) acc[i][j] = 0.0f;

        for (int dc = 0; dc < D; dc += TD) {
            __syncthreads();   // protect cs from previous iteration's readers
            {
                // stage cb tile: 128 codes x 32 d = 1024 float4, 4 per thread
                int c  = tid >> 3;
                int c4 = (tid & 7) * 4;
                #pragma unroll
                for (int i = 0; i < 4; ++i) {
                    *reinterpret_cast<float4*>(&cs[(c + 32 * i) * CS + c4]) =
                        *reinterpret_cast<const float4*>(
                            cb + (size_t)(k0 + c + 32 * i) * D + dc + c4);
                }
            }
            __syncthreads();

            for (int d4 = 0; d4 < TD; d4 += 4) {
                float4 a[8], b[8];
                #pragma unroll
                for (int i = 0; i < 8; ++i)
                    a[i] = *reinterpret_cast<const float4*>(
                               &zs[(ty + 16 * i) * ZS + dc + d4]);
                #pragma unroll
                for (int j = 0; j < 8; ++j)
                    b[j] = *reinterpret_cast<const float4*>(
                               &cs[(tx + 16 * j) * CS + d4]);
                #pragma unroll
                for (int i = 0; i < 8; ++i)
                    #pragma unroll
                    for (int j = 0; j < 8; ++j)
                        acc[i][j] += a[i].x * b[j].x + a[i].y * b[j].y
                                   + a[i].z * b[j].z + a[i].w * b[j].w;
            }
        }

        // score = e_sq - 2*dot ; strict < keeps earliest (codes ascend per thread)
        #pragma unroll
        for (int j = 0; j < 8; ++j) {
            int code = k0 + tx + 16 * j;
            float es = esq[code];
            #pragma unroll
            for (int i = 0; i < 8; ++i) {
                float score = fmaf(-2.0f, acc[i][j], es);
                if (score < minv[i]) { minv[i] = score; mini[i] = code; }
            }
        }
    }

    // Reduce across the 16 lanes (tx) sharing each row; tie -> lower index.
    float* out_idx = out + (size_t)N * D;
    #pragma unroll
    for (int i = 0; i < 8; ++i) {
        float v   = minv[i];
        int   idx = mini[i];
        #pragma unroll
        for (int m = 1; m < 16; m <<= 1) {
            float ov = __shfl_xor(v, m);
            int   oi = __shfl_xor(idx, m);
            if (ov < v || (ov == v && oi < idx)) { v = ov; idx = oi; }
        }
        size_t row = row0 + ty + 16 * i;
        if (tx == 0) out_idx[row] = (float)idx;
        // gather embedding: 16 lanes copy 256 floats (64 float4) coalesced
        const float4* src = reinterpret_cast<const float4*>(cb + (size_t)idx * D);
        float4*       dst = reinterpret_cast<float4*>(out + row * D);
        #pragma unroll
        for (int t = 0; t < 4; ++t) dst[tx + 16 * t] = src[tx + 16 * t];
    }
}

extern "C" void kernel_launch(void* const* d_in, const int* in_sizes, int n_in,
                              void* d_out, int out_size, void* d_ws, size_t ws_size,
                              hipStream_t stream) {
    const float* z   = (const float*)d_in[0];
    const float* cb  = (const float*)d_in[1];
    float*       esq = (float*)d_ws;          // 8192 floats = 32 KB scratch
    float*       out = (float*)d_out;         // [N*D] embedding, then [N] indices

    esq_kernel<<<(K * 64) / 256, 256, 0, stream>>>(cb, esq);
    vq_kernel<<<N / BM, 256, 0, stream>>>(z, cb, esq, out);
}

// Round 2
// 418.518 us; speedup vs baseline: 5.4500x; 5.4500x over previous
//
#include <hip/hip_runtime.h>

constexpr int D  = 256;
constexpr int K  = 8192;
constexpr int N  = 32768;   // B*S

typedef _Float16 f16;
typedef f16   f16x8 __attribute__((ext_vector_type(8)));
typedef f16   f16x4 __attribute__((ext_vector_type(4)));
typedef float f32x4 __attribute__((ext_vector_type(4)));

// ============================================================================
// Path A (fast): fp16 3-split MFMA.  dot = zh*eh + (zl'*eh + zh*el')/1024
// cbf layout: per code k, 512 f16: [eh(256) | el'(256)], row stride 1024 B.
// ============================================================================

__global__ void cvt_cb(const float* __restrict__ cb, f16* __restrict__ cbf,
                       float* __restrict__ esq) {
    const int code = (int)((blockIdx.x * (size_t)blockDim.x + threadIdx.x) >> 6);
    const int l    = threadIdx.x & 63;
    const float4 v = *reinterpret_cast<const float4*>(cb + (size_t)code * D + l * 4);
    float s = v.x * v.x + v.y * v.y + v.z * v.z + v.w * v.w;
    #pragma unroll
    for (int m = 32; m >= 1; m >>= 1) s += __shfl_xor(s, m);
    float vf[4] = {v.x, v.y, v.z, v.w};
    f16x4 h, lo;
    #pragma unroll
    for (int j = 0; j < 4; ++j) {
        f16 hh = (f16)vf[j];
        h[j]  = hh;
        lo[j] = (f16)((vf[j] - (float)hh) * 1024.0f);
    }
    *reinterpret_cast<f16x4*>(cbf + (size_t)code * 512 + l * 4)       = h;
    *reinterpret_cast<f16x4*>(cbf + (size_t)code * 512 + 256 + l * 4) = lo;
    if (l == 0) esq[code] = s;
}

// Block: 256 threads = 4 waves; wave owns 16 z-rows (A-frags in registers).
// k-tile: 128 codes; 16 chunk-phases each (8 x eh, 8 x el'), chunk = 128x32 f16.
__launch_bounds__(256, 2)
__global__ void vq_mfma(const float* __restrict__ z, const f16* __restrict__ cbf,
                        const float* __restrict__ esq, const float* __restrict__ cb,
                        float* __restrict__ out) {
    __shared__ f16 chunk[2][4096];   // 2 x 8 KB double buffer

    const int tid = threadIdx.x;
    const int w   = tid >> 6;
    const int l   = tid & 63;
    const int l15 = l & 15;
    const int lg  = l >> 4;
    const size_t wrow0 = (size_t)blockIdx.x * 64 + w * 16;

    // ---- A fragments: zh/zl' for 16 rows, all 8 k-chunks, in registers ----
    f16x8 zh[8], zl[8];
    {
        const float* zr = z + (wrow0 + l15) * D + lg * 8;
        #pragma unroll
        for (int u = 0; u < 8; ++u) {
            float4 a = *reinterpret_cast<const float4*>(zr + u * 32);
            float4 b = *reinterpret_cast<const float4*>(zr + u * 32 + 4);
            float zf[8] = {a.x, a.y, a.z, a.w, b.x, b.y, b.z, b.w};
            f16x8 h, lo;
            #pragma unroll
            for (int e = 0; e < 8; ++e) {
                f16 hh = (f16)zf[e];
                h[e]  = hh;
                lo[e] = (f16)((zf[e] - (float)hh) * 1024.0f);
            }
            zh[u] = h; zl[u] = lo;
        }
    }

    float minv[4];
    int   mini[4];
    #pragma unroll
    for (int r = 0; r < 4; ++r) { minv[r] = 3.0e38f; mini[r] = 0; }

    f32x4 accA[8], accB[8];
    #pragma unroll
    for (int fj = 0; fj < 8; ++fj) { accA[fj] = (f32x4)0.0f; accB[fj] = (f32x4)0.0f; }

    // staging regs (thread t covers quads 2t, 2t+1 = 32 contiguous bytes)
    int4 r0, r1;
    const int Q0 = tid * 2;
    const int A0 = Q0 ^ ((Q0 >> 3) & 3);             // swizzled LDS quad
    const int A1 = (Q0 + 1) ^ (((Q0 + 1) >> 3) & 3);
    // B-frag swizzled read base (quad units): l15*4 + (lg ^ ((l15>>1)&3))
    const int rbase = (l15 * 4 + (lg ^ ((l15 >> 1) & 3))) * 8;   // f16 units

    auto stage_load = [&](int kt2, int p2) {
        const int colf = (p2 < 8) ? p2 * 32 : 256 + (p2 - 8) * 32;
        const f16* s0 = cbf + (size_t)(kt2 * 128 + (Q0 >> 2)) * 512 + colf + (Q0 & 3) * 8;
        r0 = *reinterpret_cast<const int4*>(s0);
        r1 = *reinterpret_cast<const int4*>(s0 + 8);
    };

    // prologue: chunk (kt=0, p=0) into buf 0
    stage_load(0, 0);
    {
        f16* base = &chunk[0][0];
        *reinterpret_cast<int4*>(base + A0 * 8) = r0;
        *reinterpret_cast<int4*>(base + A1 * 8) = r1;
    }

    for (int kt = 0; kt < 64; ++kt) {
        #pragma unroll
        for (int p = 0; p < 16; ++p) {
            const bool last = (kt == 63) && (p == 15);
            if (!last) stage_load(kt + (p == 15 ? 1 : 0), (p + 1) & 15);

            __syncthreads();

            // ---- compute phase p from chunk[p&1] ----
            const f16* ch = &chunk[p & 1][0];
            f16x8 b[8];
            #pragma unroll
            for (int fj = 0; fj < 8; ++fj)
                b[fj] = *reinterpret_cast<const f16x8*>(ch + rbase + fj * 512);

            if (p < 8) {
                const int u = p;
                #pragma unroll
                for (int fj = 0; fj < 8; ++fj) {
                    accA[fj] = __builtin_amdgcn_mfma_f32_16x16x32_f16(zh[u], b[fj], accA[fj], 0, 0, 0);
                    accB[fj] = __builtin_amdgcn_mfma_f32_16x16x32_f16(zl[u], b[fj], accB[fj], 0, 0, 0);
                }
            } else {
                const int u = p - 8;
                #pragma unroll
                for (int fj = 0; fj < 8; ++fj)
                    accB[fj] = __builtin_amdgcn_mfma_f32_16x16x32_f16(zh[u], b[fj], accB[fj], 0, 0, 0);
            }

            if (p == 15) {
                // ---- k-tile epilogue: scores + running argmin ----
                #pragma unroll
                for (int fj = 0; fj < 8; ++fj) {
                    const int code = kt * 128 + fj * 16 + l15;
                    const float es = esq[code];
                    f32x4 dot = accA[fj] + accB[fj] * (1.0f / 1024.0f);
                    #pragma unroll
                    for (int r = 0; r < 4; ++r) {
                        float s = fmaf(-2.0f, dot[r], es);
                        if (s < minv[r]) { minv[r] = s; mini[r] = code; }
                    }
                    accA[fj] = (f32x4)0.0f;
                    accB[fj] = (f32x4)0.0f;
                }
            }

            if (!last) {
                f16* base = &chunk[(p + 1) & 1][0];
                *reinterpret_cast<int4*>(base + A0 * 8) = r0;
                *reinterpret_cast<int4*>(base + A1 * 8) = r1;
            }
        }
    }

    // ---- final: 16-lane merge per row (tie -> lower index), gather, write ----
    float* out_idx = out + (size_t)N * D;
    #pragma unroll
    for (int r = 0; r < 4; ++r) {
        float v   = minv[r];
        int   idx = mini[r];
        #pragma unroll
        for (int m = 1; m < 16; m <<= 1) {
            float ov = __shfl_xor(v, m);
            int   oi = __shfl_xor(idx, m);
            if (ov < v || (ov == v && oi < idx)) { v = ov; idx = oi; }
        }
        const size_t row = wrow0 + lg * 4 + r;
        if (l15 == 0) out_idx[row] = (float)idx;
        const float4* src = reinterpret_cast<const float4*>(cb + (size_t)idx * D);
        float4*       dst = reinterpret_cast<float4*>(out + row * D);
        #pragma unroll
        for (int it = 0; it < 4; ++it) dst[l15 + 16 * it] = src[l15 + 16 * it];
    }
}

// ============================================================================
// Path B (fallback if ws too small): round-1 fp32 kernels (verified exact).
// ============================================================================
constexpr int BM = 128, BN = 128, TD = 32, ZS = 260, CS = 36;

__global__ void esq_kernel(const float* __restrict__ cb, float* __restrict__ esq) {
    const int lane = threadIdx.x & 63;
    const int code = (int)((blockIdx.x * (size_t)blockDim.x + threadIdx.x) >> 6);
    const float4 v = *reinterpret_cast<const float4*>(cb + (size_t)code * D + lane * 4);
    float s = v.x * v.x + v.y * v.y + v.z * v.z + v.w * v.w;
    #pragma unroll
    for (int m = 32; m >= 1; m >>= 1) s += __shfl_xor(s, m);
    if (lane == 0) esq[code] = s;
}

__launch_bounds__(256)
__global__ void vq_kernel(const float* __restrict__ z, const float* __restrict__ cb,
                          const float* __restrict__ esq, float* __restrict__ out) {
    __shared__ float zs[BM * ZS];
    __shared__ float cs[BN * CS];
    const int tid = threadIdx.x;
    const int tx  = tid & 15;
    const int ty  = tid >> 4;
    const size_t row0 = (size_t)blockIdx.x * BM;
    #pragma unroll
    for (int i = 0; i < 32; ++i) {
        int f  = tid + i * 256;
        int r  = f >> 6;
        int c4 = (f & 63) * 4;
        *reinterpret_cast<float4*>(&zs[r * ZS + c4]) =
            *reinterpret_cast<const float4*>(z + (row0 + r) * D + c4);
    }
    float minv[8]; int mini[8];
    #pragma unroll
    for (int i = 0; i < 8; ++i) { minv[i] = 3.4e38f; mini[i] = 0; }
    for (int k0 = 0; k0 < K; k0 += BN) {
        float acc[8][8];
        #pragma unroll
        for (int i = 0; i < 8; ++i)
            #pragma unroll
            for (int j = 0; j < 8; ++j) acc[i][j] = 0.0f;
        for (int dc = 0; dc < D; dc += TD) {
            __syncthreads();
            int c = tid >> 3, c4 = (tid & 7) * 4;
            #pragma unroll
            for (int i = 0; i < 4; ++i)
                *reinterpret_cast<float4*>(&cs[(c + 32 * i) * CS + c4]) =
                    *reinterpret_cast<const float4*>(cb + (size_t)(k0 + c + 32 * i) * D + dc + c4);
            __syncthreads();
            for (int d4 = 0; d4 < TD; d4 += 4) {
                float4 a[8], b[8];
                #pragma unroll
                for (int i = 0; i < 8; ++i)
                    a[i] = *reinterpret_cast<const float4*>(&zs[(ty + 16 * i) * ZS + dc + d4]);
                #pragma unroll
                for (int j = 0; j < 8; ++j)
                    b[j] = *reinterpret_cast<const float4*>(&cs[(tx + 16 * j) * CS + d4]);
                #pragma unroll
                for (int i = 0; i < 8; ++i)
                    #pragma unroll
                    for (int j = 0; j < 8; ++j)
                        acc[i][j] += a[i].x * b[j].x + a[i].y * b[j].y
                                   + a[i].z * b[j].z + a[i].w * b[j].w;
            }
        }
        #pragma unroll
        for (int j = 0; j < 8; ++j) {
            int code = k0 + tx + 16 * j;
            float es = esq[code];
            #pragma unroll
            for (int i = 0; i < 8; ++i) {
                float score = fmaf(-2.0f, acc[i][j], es);
                if (score < minv[i]) { minv[i] = score; mini[i] = code; }
            }
        }
    }
    float* out_idx = out + (size_t)N * D;
    #pragma unroll
    for (int i = 0; i < 8; ++i) {
        float v = minv[i]; int idx = mini[i];
        #pragma unroll
        for (int m = 1; m < 16; m <<= 1) {
            float ov = __shfl_xor(v, m);
            int   oi = __shfl_xor(idx, m);
            if (ov < v || (ov == v && oi < idx)) { v = ov; idx = oi; }
        }
        size_t row = row0 + ty + 16 * i;
        if (tx == 0) out_idx[row] = (float)idx;
        const float4* src = reinterpret_cast<const float4*>(cb + (size_t)idx * D);
        float4*       dst = reinterpret_cast<float4*>(out + row * D);
        #pragma unroll
        for (int t = 0; t < 4; ++t) dst[tx + 16 * t] = src[tx + 16 * t];
    }
}

extern "C" void kernel_launch(void* const* d_in, const int* in_sizes, int n_in,
                              void* d_out, int out_size, void* d_ws, size_t ws_size,
                              hipStream_t stream) {
    const float* z  = (const float*)d_in[0];
    const float* cb = (const float*)d_in[1];
    float*       out = (float*)d_out;

    const size_t cbf_bytes = (size_t)K * 512 * sizeof(f16);   // 8 MB
    const size_t need = cbf_bytes + (size_t)K * sizeof(float);

    if (ws_size >= need) {
        f16*   cbf  = (f16*)d_ws;
        float* esqp = (float*)((char*)d_ws + cbf_bytes);
        cvt_cb<<<K / 4, 256, 0, stream>>>(cb, cbf, esqp);
        vq_mfma<<<N / 64, 256, 0, stream>>>(z, cbf, esqp, cb, out);
    } else {
        float* esqp = (float*)d_ws;
        esq_kernel<<<(K * 64) / 256, 256, 0, stream>>>(cb, esqp);
        vq_kernel<<<N / BM, 256, 0, stream>>>(z, cb, esqp, out);
    }
}